// Round 4
// baseline (471.556 us; speedup 1.0000x reference)
//
#include <hip/hip_runtime.h>

#define Bsz 4096
#define Tt  256
#define Ff  32
#define H1  64
#define H2  32
#define NTAPS 3
#define BT  8       // 512 blocks -> 2 blocks/CU, 4 waves/SIMD (2 indep chains)
#define NTHR 512    // 8 waves: 0-3 L1, 4-7 L2(split)+XG+DMA
#define CH  16      // x-staging chunk (timesteps)

typedef _Float16 half8  __attribute__((ext_vector_type(8)));
typedef __fp16   fp16x2 __attribute__((ext_vector_type(2)));   // cvt_pkrtz return type
typedef float    f32x4  __attribute__((ext_vector_type(4)));

#define H1S 72   // f16 row strides (16B-aligned, bank-spread)
#define H2S 40
#define HDS 33

// fused LSTM unit: 5 exp + 2 rcp (f/ig reciprocals merged, algebraically exact)
__device__ __forceinline__ float lstm_unit(float pi, float pf, float pg, float po,
                                           float& c) {
    const float K1 = 1.4426950408889634f;   // log2(e)
    float ei = __builtin_amdgcn_exp2f(-K1 * pi);
    float ef = __builtin_amdgcn_exp2f(-K1 * pf);
    float eg = __builtin_amdgcn_exp2f(-2.0f * K1 * __builtin_fabsf(pg));
    float eo = __builtin_amdgcn_exp2f(-K1 * po);
    float p1 = (1.0f + ei) * (1.0f + eg);
    float pf1 = 1.0f + ef;
    float R  = __builtin_amdgcn_rcpf(p1 * pf1);          // 1/((1+ei)(1+eg)(1+ef))
    float t1 = c * p1;                                    // c*(1+ei)(1+eg)
    float t2 = __builtin_copysignf(1.0f - eg, pg) * pf1;  // tanh(g)num*sig(i)num*(1+ef)
    c = (t1 + t2) * R;                                    // f*c + i*g
    float ec = __builtin_amdgcn_exp2f(-2.0f * K1 * __builtin_fabsf(c));
    float th = (1.0f - ec) * __builtin_amdgcn_rcpf((1.0f + eo) * (1.0f + ec));
    return __builtin_copysignf(th, c);                    // o*tanh(c)
}

#define MFMA16(a, b, c) __builtin_amdgcn_mfma_f32_16x16x32_f16((a), (b), (c), 0, 0, 0)

// async global->LDS DMA, 16B per lane; LDS dst = uniform base + lane*16
__device__ __forceinline__ void dma16(const float* gp, const float* lp) {
    __builtin_amdgcn_global_load_lds(
        (const __attribute__((address_space(1))) void*)gp,
        (__attribute__((address_space(3))) void*)lp, 16, 0, 0);
}

__device__ __forceinline__ half8 cvt8(f32x4 lo, f32x4 hi) {
    union { half8 v; fp16x2 h[4]; } ax;
    ax.h[0] = __builtin_amdgcn_cvt_pkrtz(lo[0], lo[1]);
    ax.h[1] = __builtin_amdgcn_cvt_pkrtz(lo[2], lo[3]);
    ax.h[2] = __builtin_amdgcn_cvt_pkrtz(hi[0], hi[1]);
    ax.h[3] = __builtin_amdgcn_cvt_pkrtz(hi[2], hi[3]);
    return ax.v;
}

__global__ __launch_bounds__(NTHR, 4)
void lstm2_fused(const float* __restrict__ x,
                 const float* __restrict__ Wih1, const float* __restrict__ Whh1,
                 const float* __restrict__ bih1, const float* __restrict__ bhh1,
                 const float* __restrict__ Wih2, const float* __restrict__ Whh2,
                 const float* __restrict__ bih2, const float* __restrict__ bhh2,
                 const float* __restrict__ Whead, const float* __restrict__ bhead,
                 float* __restrict__ out)
{
    __shared__ __align__(16) _Float16 sH1[2][BT][H1S];        // 2.25 KB
    __shared__ __align__(16) _Float16 sH2[2][BT][H2S];        // 1.25 KB
    // x chunk: [buf][t][f4][b][4] f32 — (f4-major, b-minor) so DMA lane*16B is contiguous
    __shared__ __align__(16) float    sXC[2][CH][8][BT][4];   // 32 KB
    // precomputed x-gates: [buf][h-tile][gate][lane][4] f32 (lane-linear)
    __shared__ __align__(16) float    sXG[2][4][4][64][4];    // 32 KB
    __shared__ __align__(16) float    sHead[BT][HDS];         // 1 KB

    const int tid  = threadIdx.x;
    const int wid  = tid >> 6;        // 0..7
    const int lane = tid & 63;
    const int l15  = lane & 15;
    const int q    = lane >> 4;       // 0..3
    const int row8 = l15 & 7;         // A-frag rows duplicate with period 8 (BT=8)
    const int b0   = blockIdx.x * BT;
    const int u    = wid & 3;         // L1: h-tile; L2/XG: sub-role index
    const bool isL1 = (wid < 4);

    // L1: wave owns h1-tile u; each lane applies lstm to 2 of its 4 acc rows
    const int colL1 = u * 16 + l15;
    const int r0  = (q >> 1) * 2, r1v = r0 + 1;
    const int bLo = (q & 1) * 4 + (q >> 1) * 2;
    // L2: pairs (u&1 = tile), rh = u>>1 splits the 2 valid rows -> 1 lstm/lane
    const int hT = u & 1, rh = u >> 1;
    const int rL2 = (q >> 1) * 2 + rh;
    const int bL2 = (q & 1) * 4 + (q >> 1) * 2 + rh;

    // per-lane DMA source base: batch bL, float-quad f4L
    const int bL  = lane & 7;
    const int f4L = lane >> 3;
    const float* gbase = x + (size_t)(b0 + bL) * Tt * Ff + f4L * 4;

    // ---- prologue: waves 4-7 kick chunk 0 DMA immediately ----
    if (!isL1) {
        #pragma unroll
        for (int j = 0; j < 4; ++j) {
            int tl = u * 4 + j;
            dma16(gbase + (size_t)tl * Ff, &sXC[0][tl][0][0][0]);
        }
    }

    // ---- weight fragments (registers, one time) ----
    half8 wL[4][3];     // L1: [G][0,1] h1-part; L2: [G][0] h2, [G][1,2] h1
    half8 wX[4];        // XG: x->gate frags (waves 4-7 only)
    float biasA[4], biasX[4];
    if (isL1) {
        #pragma unroll
        for (int G = 0; G < 4; ++G) {
            int gr = G * 64 + colL1;               // L1 gate row
            #pragma unroll
            for (int c = 0; c < 2; ++c) {
                half8 v;
                #pragma unroll
                for (int e = 0; e < 8; ++e)
                    v[e] = (_Float16)Whh1[gr * H1 + c * 32 + q * 8 + e];
                wL[G][c] = v;
            }
            wL[G][2] = wL[G][1];   // unused on L1 path
            biasA[G] = 0.0f;
            biasX[G] = 0.0f;
        }
    } else {
        #pragma unroll
        for (int G = 0; G < 4; ++G) {
            int gr2 = G * 32 + hT * 16 + l15;      // L2 gate row
            half8 v0, v1, v2, vx;
            #pragma unroll
            for (int e = 0; e < 8; ++e) {
                int k = q * 8 + e;
                v0[e] = (_Float16)Whh2[gr2 * H2 + k];
                v1[e] = (_Float16)Wih2[gr2 * H1 + k];
                v2[e] = (_Float16)Wih2[gr2 * H1 + 32 + k];
            }
            wL[G][0] = v0; wL[G][1] = v1; wL[G][2] = v2;
            biasA[G] = bih2[gr2] + bhh2[gr2];

            int grx = G * 64 + u * 16 + l15;       // XG gate row (tile u)
            #pragma unroll
            for (int e = 0; e < 8; ++e)
                vx[e] = (_Float16)Wih1[grx * Ff + q * 8 + e];
            wX[G] = vx;
            biasX[G] = bih1[grx] + bhh1[grx];
        }
    }

    // ---- zero h(-1) buffers ----
    for (int idx = tid; idx < BT * H1S; idx += NTHR) ((_Float16*)sH1[1])[idx] = (_Float16)0.0f;
    for (int idx = tid; idx < BT * H2S; idx += NTHR) ((_Float16*)sH2[1])[idx] = (_Float16)0.0f;

    __syncthreads();   // drains chunk-0 DMA + init writes

    // ---- XG prologue: xg(0) into sXG[0] ----
    if (!isL1) {
        f32x4 lo = *(const f32x4*)&sXC[0][0][2 * q][row8][0];
        f32x4 hi = *(const f32x4*)&sXC[0][0][2 * q + 1][row8][0];
        half8 ax = cvt8(lo, hi);
        #pragma unroll
        for (int G = 0; G < 4; ++G) {
            f32x4 a = {biasX[G], biasX[G], biasX[G], biasX[G]};
            a = MFMA16(ax, wX[G], a);
            *(f32x4*)&sXG[0][u][G][lane][0] = a;
        }
    }
    __syncthreads();

    float cs0 = 0.0f, cs1 = 0.0f;

    #pragma unroll 2
    for (int i = 0; i < Tt; ++i) {
        const int cur = i & 1, nxt = cur ^ 1;
        const int cbuf = (i >> 4) & 1;

        // ---- chunk-boundary DMA at TOP of step (latency hides under compute) ----
        if (!isL1 && (i & (CH - 1)) == 0 && i + CH < Tt) {
            const float* gb = gbase + (size_t)(i + CH) * Ff;
            #pragma unroll
            for (int j = 0; j < 4; ++j) {
                int tl = u * 4 + j;
                dma16(gb + (size_t)tl * Ff, &sXC[cbuf ^ 1][tl][0][0][0]);
            }
        }

        // h1(i-1) fragments (L1 A-operand; L2 K-part operand)
        half8 a0 = *(const half8*)&sH1[nxt][row8][q * 8];
        half8 a1 = *(const half8*)&sH1[nxt][row8][32 + q * 8];

        if (isL1) {   // ---- L1 step i: C-init from precomputed xg, 8 MFMAs, 2 lstm ----
            f32x4 acc[4];
            #pragma unroll
            for (int G = 0; G < 4; ++G) {
                f32x4 a = *(const f32x4*)&sXG[cur][u][G][lane][0];
                a = MFMA16(a0, wL[G][0], a);
                a = MFMA16(a1, wL[G][1], a);
                acc[G] = a;
            }
            float h0  = lstm_unit(acc[0][r0],  acc[1][r0],  acc[2][r0],  acc[3][r0],  cs0);
            float h1v = lstm_unit(acc[0][r1v], acc[1][r1v], acc[2][r1v], acc[3][r1v], cs1);
            sH1[cur][bLo][colL1]     = (_Float16)h0;
            sH1[cur][bLo + 1][colL1] = (_Float16)h1v;
        } else {
            if (i >= 1) {   // ---- L2 step i-1 (MFMAs duplicated per pair; 1 lstm/lane) ----
                half8 ah = *(const half8*)&sH2[cur][row8][q * 8];
                f32x4 acc[4];
                #pragma unroll
                for (int G = 0; G < 4; ++G) {
                    f32x4 a = {biasA[G], biasA[G], biasA[G], biasA[G]};
                    a = MFMA16(ah, wL[G][0], a);
                    a = MFMA16(a0, wL[G][1], a);
                    a = MFMA16(a1, wL[G][2], a);
                    acc[G] = a;
                }
                float hA = lstm_unit(acc[0][rL2], acc[1][rL2], acc[2][rL2], acc[3][rL2], cs0);
                sH2[nxt][bL2][hT * 16 + l15] = (_Float16)hA;
            }
            if (i + 1 < Tt) {   // ---- XG: xg(i+1) into sXG[nxt] ----
                const int t = i + 1, cb = (t >> 4) & 1, t16 = t & (CH - 1);
                f32x4 lo = *(const f32x4*)&sXC[cb][t16][2 * q][row8][0];
                f32x4 hi = *(const f32x4*)&sXC[cb][t16][2 * q + 1][row8][0];
                half8 ax = cvt8(lo, hi);
                #pragma unroll
                for (int G = 0; G < 4; ++G) {
                    f32x4 a = {biasX[G], biasX[G], biasX[G], biasX[G]};
                    a = MFMA16(ax, wX[G], a);
                    *(f32x4*)&sXG[nxt][u][G][lane][0] = a;
                }
            }
        }

        __syncthreads();   // single barrier per step
    }

    // ---- epilogue: final L2 step (t = Tt-1) -> sHead ----
    {
        const int cur = Tt & 1;        // 0
        const int nxt = cur ^ 1;       // 1
        if (!isL1) {
            half8 a0 = *(const half8*)&sH1[nxt][row8][q * 8];
            half8 a1 = *(const half8*)&sH1[nxt][row8][32 + q * 8];
            half8 ah = *(const half8*)&sH2[cur][row8][q * 8];
            f32x4 acc[4];
            #pragma unroll
            for (int G = 0; G < 4; ++G) {
                f32x4 a = {biasA[G], biasA[G], biasA[G], biasA[G]};
                a = MFMA16(ah, wL[G][0], a);
                a = MFMA16(a0, wL[G][1], a);
                a = MFMA16(a1, wL[G][2], a);
                acc[G] = a;
            }
            float hA = lstm_unit(acc[0][rL2], acc[1][rL2], acc[2][rL2], acc[3][rL2], cs0);
            sHead[bL2][hT * 16 + l15] = hA;
        }
        __syncthreads();
    }

    // ---- head ----
    if (tid < BT * NTAPS) {
        int b = tid / NTAPS, n = tid - b * NTAPS;
        float s = bhead[n];
        #pragma unroll
        for (int k = 0; k < H2; ++k) s = fmaf(sHead[b][k], Whead[n * H2 + k], s);
        out[(size_t)(b0 + b) * NTAPS + n] = s;
    }
}

extern "C" void kernel_launch(void* const* d_in, const int* in_sizes, int n_in,
                              void* d_out, int out_size, void* d_ws, size_t ws_size,
                              hipStream_t stream) {
    const float* xp    = (const float*)d_in[0];
    const float* Wih1  = (const float*)d_in[1];
    const float* Whh1  = (const float*)d_in[2];
    const float* bih1  = (const float*)d_in[3];
    const float* bhh1  = (const float*)d_in[4];
    const float* Wih2  = (const float*)d_in[5];
    const float* Whh2  = (const float*)d_in[6];
    const float* bih2  = (const float*)d_in[7];
    const float* bhh2  = (const float*)d_in[8];
    const float* Whead = (const float*)d_in[9];
    const float* bhead = (const float*)d_in[10];
    float* outp = (float*)d_out;

    hipLaunchKernelGGL(lstm2_fused, dim3(Bsz / BT), dim3(NTHR), 0, stream,
                       xp, Wih1, Whh1, bih1, bhh1, Wih2, Whh2, bih2, bhh2,
                       Whead, bhead, outp);
}

// Round 5
// 383.034 us; speedup vs baseline: 1.2311x; 1.2311x over previous
//
#include <hip/hip_runtime.h>

#define Bsz 4096
#define Tt  256
#define Ff  32
#define H1  64
#define H2  32
#define NTAPS 3
#define BT  8       // 512 blocks -> 2 blocks/CU, 4 waves/SIMD (2 indep chains/SIMD)
#define NTHR 512    // 8 waves: 0-3 L1+XG(reg-held), 4-7 L2+DMA
#define CH  16      // x-staging chunk (timesteps)

typedef _Float16 half8  __attribute__((ext_vector_type(8)));
typedef __fp16   fp16x2 __attribute__((ext_vector_type(2)));   // cvt_pkrtz return type
typedef float    f32x4  __attribute__((ext_vector_type(4)));

#define H1S 72   // f16 row strides (16B-aligned, bank-spread)
#define H2S 40
#define HDS 33

// fused LSTM unit: 5 exp + 2 rcp (f/ig reciprocals merged, algebraically exact)
__device__ __forceinline__ float lstm_unit(float pi, float pf, float pg, float po,
                                           float& c) {
    const float K1 = 1.4426950408889634f;   // log2(e)
    float ei = __builtin_amdgcn_exp2f(-K1 * pi);
    float ef = __builtin_amdgcn_exp2f(-K1 * pf);
    float eg = __builtin_amdgcn_exp2f(-2.0f * K1 * __builtin_fabsf(pg));
    float eo = __builtin_amdgcn_exp2f(-K1 * po);
    float p1 = (1.0f + ei) * (1.0f + eg);
    float pf1 = 1.0f + ef;
    float R  = __builtin_amdgcn_rcpf(p1 * pf1);          // 1/((1+ei)(1+eg)(1+ef))
    float t1 = c * p1;                                    // c*(1+ei)(1+eg)
    float t2 = __builtin_copysignf(1.0f - eg, pg) * pf1;  // tanh(g)num*sig(i)num*(1+ef)
    c = (t1 + t2) * R;                                    // f*c + i*g
    float ec = __builtin_amdgcn_exp2f(-2.0f * K1 * __builtin_fabsf(c));
    float th = (1.0f - ec) * __builtin_amdgcn_rcpf((1.0f + eo) * (1.0f + ec));
    return __builtin_copysignf(th, c);                    // o*tanh(c)
}

#define MFMA16(a, b, c) __builtin_amdgcn_mfma_f32_16x16x32_f16((a), (b), (c), 0, 0, 0)

// async global->LDS DMA, 16B per lane; LDS dst = uniform base + lane*16
__device__ __forceinline__ void dma16(const float* gp, const float* lp) {
    __builtin_amdgcn_global_load_lds(
        (const __attribute__((address_space(1))) void*)gp,
        (__attribute__((address_space(3))) void*)lp, 16, 0, 0);
}

__device__ __forceinline__ half8 cvt8(f32x4 lo, f32x4 hi) {
    union { half8 v; fp16x2 h[4]; } ax;
    ax.h[0] = __builtin_amdgcn_cvt_pkrtz(lo[0], lo[1]);
    ax.h[1] = __builtin_amdgcn_cvt_pkrtz(lo[2], lo[3]);
    ax.h[2] = __builtin_amdgcn_cvt_pkrtz(hi[0], hi[1]);
    ax.h[3] = __builtin_amdgcn_cvt_pkrtz(hi[2], hi[3]);
    return ax.v;
}

// launch_bounds(NTHR,2): empirically (NTHR,4) hard-caps VGPR at 64 -> loop spills
// (r4: WRITE_SIZE 48KB->14.6MB). (NTHR,2) allows ~128; demand ~115 -> no spill,
// and LDS (~38KB) + VGPR<=128 still co-resides 2 blocks/CU (4 waves/SIMD).
__global__ __launch_bounds__(NTHR, 2)
void lstm2_fused(const float* __restrict__ x,
                 const float* __restrict__ Wih1, const float* __restrict__ Whh1,
                 const float* __restrict__ bih1, const float* __restrict__ bhh1,
                 const float* __restrict__ Wih2, const float* __restrict__ Whh2,
                 const float* __restrict__ bih2, const float* __restrict__ bhh2,
                 const float* __restrict__ Whead, const float* __restrict__ bhead,
                 float* __restrict__ out)
{
    __shared__ __align__(16) _Float16 sH1[2][BT][H1S];        // 2.25 KB
    __shared__ __align__(16) _Float16 sH2[2][BT][H2S];        // 1.25 KB
    // x chunk: [buf][t][f4][b][4] f32 — (f4-major, b-minor) so DMA lane*16B is contiguous
    __shared__ __align__(16) float    sXC[2][CH][8][BT][4];   // 32 KB
    __shared__ __align__(16) float    sHead[BT][HDS];         // 1 KB

    const int tid  = threadIdx.x;
    const int wid  = tid >> 6;        // 0..7
    const int lane = tid & 63;
    const int l15  = lane & 15;
    const int q    = lane >> 4;       // 0..3
    const int row8 = l15 & 7;         // A-frag rows duplicate with period 8 (BT=8)
    const int b0   = blockIdx.x * BT;
    const int u    = wid & 3;         // L1: h-tile; L2: sub-role index
    const bool isL1 = (wid < 4);

    // L1: wave owns h1-tile u; each lane applies lstm to 2 of its 4 acc rows
    const int colL1 = u * 16 + l15;
    const int r0  = (q >> 1) * 2, r1v = r0 + 1;
    const int bLo = (q & 1) * 4 + (q >> 1) * 2;
    // L2: pairs (u&1 = tile), rh = u>>1 splits the rows -> 1 lstm/lane
    const int hT = u & 1, rh = u >> 1;
    const int rL2 = (q >> 1) * 2 + rh;
    const int bL2 = (q & 1) * 4 + (q >> 1) * 2 + rh;

    // per-lane DMA source base: batch bL, float-quad f4L
    const int bL  = lane & 7;
    const int f4L = lane >> 3;
    const float* gbase = x + (size_t)(b0 + bL) * Tt * Ff + f4L * 4;

    // ---- prologue: waves 4-7 kick chunk 0 DMA immediately ----
    if (!isL1) {
        #pragma unroll
        for (int j = 0; j < 4; ++j) {
            int tl = u * 4 + j;
            dma16(gbase + (size_t)tl * Ff, &sXC[0][tl][0][0][0]);
        }
    }

    // ---- weight fragments (registers, one time) ----
    // L1: [G][0,1] = Whh1 h-tiles, [G][2] = Wih1 (XG); bias[G] = bih1+bhh1 (seeds xg)
    // L2: [G][0] = Whh2, [G][1,2] = Wih2;              bias[G] = bih2+bhh2
    half8 wH[4][3];
    float bias[4];
    if (isL1) {
        #pragma unroll
        for (int G = 0; G < 4; ++G) {
            int gr = G * 64 + colL1;               // L1 gate row
            #pragma unroll
            for (int c = 0; c < 2; ++c) {
                half8 v;
                #pragma unroll
                for (int e = 0; e < 8; ++e)
                    v[e] = (_Float16)Whh1[gr * H1 + c * 32 + q * 8 + e];
                wH[G][c] = v;
            }
            half8 vx;
            #pragma unroll
            for (int e = 0; e < 8; ++e)
                vx[e] = (_Float16)Wih1[gr * Ff + q * 8 + e];
            wH[G][2] = vx;
            bias[G] = bih1[gr] + bhh1[gr];
        }
    } else {
        #pragma unroll
        for (int G = 0; G < 4; ++G) {
            int gr2 = G * 32 + hT * 16 + l15;      // L2 gate row
            half8 v0, v1, v2;
            #pragma unroll
            for (int e = 0; e < 8; ++e) {
                int k = q * 8 + e;
                v0[e] = (_Float16)Whh2[gr2 * H2 + k];
                v1[e] = (_Float16)Wih2[gr2 * H1 + k];
                v2[e] = (_Float16)Wih2[gr2 * H1 + 32 + k];
            }
            wH[G][0] = v0; wH[G][1] = v1; wH[G][2] = v2;
            bias[G] = bih2[gr2] + bhh2[gr2];
        }
    }

    // ---- zero h(-1) buffers ----
    for (int idx = tid; idx < BT * H1S; idx += NTHR) ((_Float16*)sH1[1])[idx] = (_Float16)0.0f;
    for (int idx = tid; idx < BT * H2S; idx += NTHR) ((_Float16*)sH2[1])[idx] = (_Float16)0.0f;

    __syncthreads();   // drains chunk-0 DMA + init writes

    // ---- XG prologue: xg(0) into L1-wave REGISTERS (no LDS round-trip) ----
    f32x4 xgN[4];
    if (isL1) {
        f32x4 lo = *(const f32x4*)&sXC[0][0][2 * q][row8][0];
        f32x4 hi = *(const f32x4*)&sXC[0][0][2 * q + 1][row8][0];
        half8 ax = cvt8(lo, hi);
        #pragma unroll
        for (int G = 0; G < 4; ++G) {
            f32x4 a = {bias[G], bias[G], bias[G], bias[G]};
            xgN[G] = MFMA16(ax, wH[G][2], a);
        }
    }

    float cs0 = 0.0f, cs1 = 0.0f;

    #pragma unroll 2
    for (int i = 0; i < Tt; ++i) {
        const int cur = i & 1, nxt = cur ^ 1;
        const int cbuf = (i >> 4) & 1;

        // ---- chunk-boundary DMA at TOP of step (latency hides under compute) ----
        if (!isL1 && (i & (CH - 1)) == 0 && i + CH < Tt) {
            const float* gb = gbase + (size_t)(i + CH) * Ff;
            #pragma unroll
            for (int j = 0; j < 4; ++j) {
                int tl = u * 4 + j;
                dma16(gb + (size_t)tl * Ff, &sXC[cbuf ^ 1][tl][0][0][0]);
            }
        }

        // h1(i-1) fragments (L1 A-operand; L2 K-part operand)
        half8 a0 = *(const half8*)&sH1[nxt][row8][q * 8];
        half8 a1 = *(const half8*)&sH1[nxt][row8][32 + q * 8];

        if (isL1) {   // ---- L1 step i: acc seeded from reg-held xg, 8 MFMAs, 2 lstm ----
            f32x4 acc[4];
            #pragma unroll
            for (int G = 0; G < 4; ++G) {
                f32x4 a = xgN[G];
                a = MFMA16(a0, wH[G][0], a);
                a = MFMA16(a1, wH[G][1], a);
                acc[G] = a;
            }
            float h0  = lstm_unit(acc[0][r0],  acc[1][r0],  acc[2][r0],  acc[3][r0],  cs0);
            float h1v = lstm_unit(acc[0][r1v], acc[1][r1v], acc[2][r1v], acc[3][r1v], cs1);
            sH1[cur][bLo][colL1]     = (_Float16)h0;
            sH1[cur][bLo + 1][colL1] = (_Float16)h1v;

            if (i + 1 < Tt) {   // ---- XG: xg(i+1) into registers for next step ----
                const int t = i + 1, cb = (t >> 4) & 1, t16 = t & (CH - 1);
                f32x4 lo = *(const f32x4*)&sXC[cb][t16][2 * q][row8][0];
                f32x4 hi = *(const f32x4*)&sXC[cb][t16][2 * q + 1][row8][0];
                half8 ax = cvt8(lo, hi);
                #pragma unroll
                for (int G = 0; G < 4; ++G) {
                    f32x4 a = {bias[G], bias[G], bias[G], bias[G]};
                    xgN[G] = MFMA16(ax, wH[G][2], a);
                }
            }
        } else if (i >= 1) {   // ---- L2 step i-1 (MFMAs duplicated per pair; 1 lstm/lane) ----
            half8 ah = *(const half8*)&sH2[cur][row8][q * 8];
            f32x4 acc[4];
            #pragma unroll
            for (int G = 0; G < 4; ++G) {
                f32x4 a = {bias[G], bias[G], bias[G], bias[G]};
                a = MFMA16(ah, wH[G][0], a);
                a = MFMA16(a0, wH[G][1], a);
                a = MFMA16(a1, wH[G][2], a);
                acc[G] = a;
            }
            float hA = lstm_unit(acc[0][rL2], acc[1][rL2], acc[2][rL2], acc[3][rL2], cs0);
            sH2[nxt][bL2][hT * 16 + l15] = (_Float16)hA;
        }

        __syncthreads();   // single barrier per step
    }

    // ---- epilogue: final L2 step (t = Tt-1) -> sHead ----
    {
        const int cur = Tt & 1;        // 0
        const int nxt = cur ^ 1;       // 1
        if (!isL1) {
            half8 a0 = *(const half8*)&sH1[nxt][row8][q * 8];
            half8 a1 = *(const half8*)&sH1[nxt][row8][32 + q * 8];
            half8 ah = *(const half8*)&sH2[cur][row8][q * 8];
            f32x4 acc[4];
            #pragma unroll
            for (int G = 0; G < 4; ++G) {
                f32x4 a = {bias[G], bias[G], bias[G], bias[G]};
                a = MFMA16(ah, wH[G][0], a);
                a = MFMA16(a0, wH[G][1], a);
                a = MFMA16(a1, wH[G][2], a);
                acc[G] = a;
            }
            float hA = lstm_unit(acc[0][rL2], acc[1][rL2], acc[2][rL2], acc[3][rL2], cs0);
            sHead[bL2][hT * 16 + l15] = hA;
        }
        __syncthreads();
    }

    // ---- head ----
    if (tid < BT * NTAPS) {
        int b = tid / NTAPS, n = tid - b * NTAPS;
        float s = bhead[n];
        #pragma unroll
        for (int k = 0; k < H2; ++k) s = fmaf(sHead[b][k], Whead[n * H2 + k], s);
        out[(size_t)(b0 + b) * NTAPS + n] = s;
    }
}

extern "C" void kernel_launch(void* const* d_in, const int* in_sizes, int n_in,
                              void* d_out, int out_size, void* d_ws, size_t ws_size,
                              hipStream_t stream) {
    const float* xp    = (const float*)d_in[0];
    const float* Wih1  = (const float*)d_in[1];
    const float* Whh1  = (const float*)d_in[2];
    const float* bih1  = (const float*)d_in[3];
    const float* bhh1  = (const float*)d_in[4];
    const float* Wih2  = (const float*)d_in[5];
    const float* Whh2  = (const float*)d_in[6];
    const float* bih2  = (const float*)d_in[7];
    const float* bhh2  = (const float*)d_in[8];
    const float* Whead = (const float*)d_in[9];
    const float* bhead = (const float*)d_in[10];
    float* outp = (float*)d_out;

    hipLaunchKernelGGL(lstm2_fused, dim3(Bsz / BT), dim3(NTHR), 0, stream,
                       xp, Wih1, Whh1, bih1, bhh1, Wih2, Whh2, bih2, bhh2,
                       Whead, bhead, outp);
}